// Round 1
// baseline (150.003 us; speedup 1.0000x reference)
//
#include <hip/hip_runtime.h>
#include <stdint.h>

// Quant3Linear GEMV: y = x @ (scales.T * unpack3(qweight) - zeros.T) + bias
//   x: (1, 8192) f32 | qweight: (768, 28672) i32 | scales,zeros: (28672,1) | bias: (28672,)
// Decomposition: y[o] = scales[o]*dot(x, q[:,o]) - zeros[o]*sum(x) + bias[o]

constexpr int O_FEAT  = 28672;
constexpr int IN_FEAT = 8192;
constexpr int NGROUP  = IN_FEAT / 32;   // 256 groups of 32 packed values (3 int32 rows each)
constexpr int SPLIT   = 8;              // split-K factor
constexpr int GPB     = NGROUP / SPLIT; // 32 groups per block

// Init: out[o] = bias[o] - zeros[o]*sum(x). Each block redundantly reduces x
// (32 KB, L2-resident) -- avoids a separate reduction kernel + also serves as
// the output initializer for the atomic split-K accumulation that follows.
__global__ __launch_bounds__(256) void q3_init(const float* __restrict__ x,
                                               const float* __restrict__ zeros,
                                               const float* __restrict__ bias,
                                               float* __restrict__ out) {
  float s = 0.f;
  const float4* x4 = reinterpret_cast<const float4*>(x);
  for (int i = threadIdx.x; i < IN_FEAT / 4; i += 256) {
    float4 t = x4[i];
    s += (t.x + t.y) + (t.z + t.w);
  }
  #pragma unroll
  for (int off = 32; off > 0; off >>= 1) s += __shfl_down(s, off, 64);
  __shared__ float ls[4];
  if ((threadIdx.x & 63) == 0) ls[threadIdx.x >> 6] = s;
  __syncthreads();
  float S = (ls[0] + ls[1]) + (ls[2] + ls[3]);
  int o = blockIdx.x * 256 + threadIdx.x;
  out[o] = bias[o] - zeros[o] * S;
}

// Main GEMV: one thread per output column, split-K over blockIdx.y.
// Per group g, column o: words w0,w1,w2 = qweight[3g..3g+2][o] hold 32 3-bit
// codes (GPTQ packing: 10 in w0, 1 split w0/w1, 10 in w1, 1 split w1/w2, 10 in w2).
__global__ __launch_bounds__(256) void q3_gemv(const float* __restrict__ x,
                                               const uint32_t* __restrict__ qw,
                                               const float* __restrict__ scales,
                                               float* __restrict__ out) {
  const int o  = blockIdx.x * 256 + threadIdx.x;
  const int g0 = blockIdx.y * GPB;
  // 3 independent accumulator chains to cover FMA latency.
  float acc0 = 0.f, acc1 = 0.f, acc2 = 0.f;
  const uint32_t* qp = qw + (size_t)(3 * g0) * O_FEAT + o;
  const float*    xp = x + g0 * 32;

  for (int g = 0; g < GPB; ++g) {
    uint32_t w0 = qp[0];
    uint32_t w1 = qp[O_FEAT];
    uint32_t w2 = qp[2 * O_FEAT];
    qp += 3 * O_FEAT;

    // x slice is wave-uniform (loop-indexed): expect s_load / L1-broadcast.
    float xv[32];
    const float4* x4 = reinterpret_cast<const float4*>(xp);
    #pragma unroll
    for (int u = 0; u < 8; ++u) {
      float4 t = x4[u];
      xv[4 * u + 0] = t.x; xv[4 * u + 1] = t.y;
      xv[4 * u + 2] = t.z; xv[4 * u + 3] = t.w;
    }
    xp += 32;

    #pragma unroll
    for (int j = 0; j < 10; ++j)
      acc0 += xv[j] * (float)((w0 >> (3 * j)) & 7u);
    acc0 += xv[10] * (float)((w0 >> 30) | ((w1 & 1u) << 2));
    #pragma unroll
    for (int j = 0; j < 10; ++j)
      acc1 += xv[11 + j] * (float)((w1 >> (3 * j + 1)) & 7u);
    acc1 += xv[21] * (float)((w1 >> 31) | ((w2 & 3u) << 1));
    #pragma unroll
    for (int j = 0; j < 10; ++j)
      acc2 += xv[22 + j] * (float)((w2 >> (3 * j + 2)) & 7u);
  }

  atomicAdd(&out[o], scales[o] * ((acc0 + acc1) + acc2));
}

extern "C" void kernel_launch(void* const* d_in, const int* in_sizes, int n_in,
                              void* d_out, int out_size, void* d_ws, size_t ws_size,
                              hipStream_t stream) {
  const float*    x      = (const float*)d_in[0];
  const uint32_t* qw     = (const uint32_t*)d_in[1];
  const float*    scales = (const float*)d_in[2];
  const float*    zeros  = (const float*)d_in[3];
  const float*    bias   = (const float*)d_in[4];
  float*          out    = (float*)d_out;

  q3_init<<<dim3(O_FEAT / 256), dim3(256), 0, stream>>>(x, zeros, bias, out);
  q3_gemv<<<dim3(O_FEAT / 256, SPLIT), dim3(256), 0, stream>>>(x, qw, scales, out);
}

// Round 2
// 143.475 us; speedup vs baseline: 1.0455x; 1.0455x over previous
//
#include <hip/hip_runtime.h>
#include <stdint.h>

// Quant3Linear GEMV: y = x @ (scales.T * unpack3(qweight) - zeros.T) + bias
//   x: (1, 8192) f32 | qweight: (768, 28672) i32 | scales,zeros: (28672,1) | bias: (28672,)
// Decomposition: y[o] = scales[o]*dot(x, q[:,o]) - zeros[o]*sum(x) + bias[o]
//
// Stage A (q3_partial): split-K=32, 4 columns/thread via dwordx4 qweight loads
//   (1 KB/wave/load -> latency well-hidden), partials to d_ws (no atomics).
// Stage B (q3_finish): 32-way partial reduce + bias - zeros*sum(x), one write/o.

constexpr int O_FEAT  = 28672;
constexpr int IN_FEAT = 8192;
constexpr int NGROUP  = IN_FEAT / 32;   // 256 groups (3 packed int32 rows each)
constexpr int SPLIT   = 32;             // split-K factor
constexpr int GPB     = NGROUP / SPLIT; // 8 groups per thread
constexpr int O4      = O_FEAT / 4;     // uint4 columns per packed row

// Unpack one column-group (32 3-bit codes in w0,w1,w2; GPTQ packing) and
// accumulate dot with xv[0..31]. 3 internal chains cover FMA latency.
__device__ __forceinline__ void dot_group(uint32_t w0, uint32_t w1, uint32_t w2,
                                          const float xv[32], float& acc) {
  float a0 = acc, a1 = 0.f, a2 = 0.f;
  #pragma unroll
  for (int j = 0; j < 10; ++j) a0 += xv[j] * (float)((w0 >> (3 * j)) & 7u);
  a0 += xv[10] * (float)((w0 >> 30) | ((w1 & 1u) << 2));
  #pragma unroll
  for (int j = 0; j < 10; ++j) a1 += xv[11 + j] * (float)((w1 >> (3 * j + 1)) & 7u);
  a1 += xv[21] * (float)((w1 >> 31) | ((w2 & 3u) << 1));
  #pragma unroll
  for (int j = 0; j < 10; ++j) a2 += xv[22 + j] * (float)((w2 >> (3 * j + 2)) & 7u);
  acc = a0 + (a1 + a2);
}

__global__ __launch_bounds__(256) void q3_partial(const float* __restrict__ x,
                                                  const uint4* __restrict__ qw4,
                                                  float* __restrict__ part) {
  const int tcol4 = blockIdx.x * 256 + threadIdx.x;  // index in units of 4 columns
  const int g0    = blockIdx.y * GPB;
  const uint4* qp = qw4 + (size_t)(3 * g0) * O4 + tcol4;
  const float* xp = x + g0 * 32;                     // block-uniform -> s_load path
  float acc0 = 0.f, acc1 = 0.f, acc2 = 0.f, acc3 = 0.f;

  for (int g = 0; g < GPB; ++g) {
    uint4 wa = qp[0];          // row 3g   : 4 columns' word0
    uint4 wb = qp[O4];         // row 3g+1 : word1
    uint4 wc = qp[2 * O4];     // row 3g+2 : word2
    qp += 3 * O4;

    float xv[32];
    const float4* x4 = reinterpret_cast<const float4*>(xp);
    #pragma unroll
    for (int u = 0; u < 8; ++u) {
      float4 t = x4[u];
      xv[4 * u + 0] = t.x; xv[4 * u + 1] = t.y;
      xv[4 * u + 2] = t.z; xv[4 * u + 3] = t.w;
    }
    xp += 32;

    dot_group(wa.x, wb.x, wc.x, xv, acc0);  // 4 independent chains
    dot_group(wa.y, wb.y, wc.y, xv, acc1);
    dot_group(wa.z, wb.z, wc.z, xv, acc2);
    dot_group(wa.w, wb.w, wc.w, xv, acc3);
  }

  float4 r = make_float4(acc0, acc1, acc2, acc3);
  reinterpret_cast<float4*>(part)[(size_t)blockIdx.y * O4 + tcol4] = r;
}

__global__ __launch_bounds__(256) void q3_finish(const float* __restrict__ x,
                                                 const float* __restrict__ part,
                                                 const float* __restrict__ scales,
                                                 const float* __restrict__ zeros,
                                                 const float* __restrict__ bias,
                                                 float* __restrict__ out) {
  // Block-redundant reduction of x (32 KB, L2-resident).
  float s = 0.f;
  const float4* x4 = reinterpret_cast<const float4*>(x);
  for (int i = threadIdx.x; i < IN_FEAT / 4; i += 256) {
    float4 t = x4[i];
    s += (t.x + t.y) + (t.z + t.w);
  }
  #pragma unroll
  for (int off = 32; off > 0; off >>= 1) s += __shfl_down(s, off, 64);
  __shared__ float ls[4];
  if ((threadIdx.x & 63) == 0) ls[threadIdx.x >> 6] = s;
  __syncthreads();
  float S = (ls[0] + ls[1]) + (ls[2] + ls[3]);

  int o = blockIdx.x * 256 + threadIdx.x;
  float sum = 0.f;
  #pragma unroll
  for (int y = 0; y < SPLIT; ++y) sum += part[(size_t)y * O_FEAT + o];
  out[o] = scales[o] * sum - zeros[o] * S + bias[o];
}

extern "C" void kernel_launch(void* const* d_in, const int* in_sizes, int n_in,
                              void* d_out, int out_size, void* d_ws, size_t ws_size,
                              hipStream_t stream) {
  const float* x      = (const float*)d_in[0];
  const uint4* qw4    = (const uint4*)d_in[1];
  const float* scales = (const float*)d_in[2];
  const float* zeros  = (const float*)d_in[3];
  const float* bias   = (const float*)d_in[4];
  float*       out    = (float*)d_out;
  float*       part   = (float*)d_ws;   // SPLIT * O_FEAT floats = 3.67 MB

  q3_partial<<<dim3(O_FEAT / (256 * 4), SPLIT), dim3(256), 0, stream>>>(x, qw4, part);
  q3_finish<<<dim3(O_FEAT / 256), dim3(256), 0, stream>>>(x, part, scales, zeros, bias, out);
}